// Round 2
// baseline (321.006 us; speedup 1.0000x reference)
//
#include <hip/hip_runtime.h>

#define DDIM 128

// ---------------------------------------------------------------------------
// Kernel 1: per-node precompute.
//   U[n][j] = sum_k z[n][k] * W1[k][j]          (j in 0..127)
//   V[n][j] = sum_k z[n][k] * W1[128+k][j]      (j in 0..127)
// Block: 256 threads; thread t owns combined column j=t (0..255: 0-127 -> U,
// 128-255 -> V). Each block handles a 16-node tile staged in LDS; z-tile reads
// are same-address broadcasts (conflict-free), W column reads are coalesced
// within each 128-thread half and L2-resident (W1 = 128 KB).
// ---------------------------------------------------------------------------
__global__ __launch_bounds__(256) void precompute_uv(
    const float* __restrict__ z, const float* __restrict__ W1,
    float* __restrict__ U, float* __restrict__ V, int N)
{
    __shared__ float zs[16 * DDIM];
    const int n0 = blockIdx.x * 16;
    const int t  = threadIdx.x;

    // Stage 16 x 128 z tile (8 KB) with float4 loads.
    {
        const float4* zg  = (const float4*)(z + (size_t)n0 * DDIM);
        float4*       zs4 = (float4*)zs;
        #pragma unroll
        for (int i = t; i < 16 * DDIM / 4; i += 256) {
            int node = n0 + (i >> 5);           // 32 float4 per node row
            zs4[i] = (node < N) ? zg[i] : make_float4(0.f, 0.f, 0.f, 0.f);
        }
    }
    __syncthreads();

    const int j = t;
    const float* wcol = (j < DDIM) ? (W1 + j) : (W1 + DDIM * DDIM + (j - DDIM));

    float acc[16];
    #pragma unroll
    for (int n = 0; n < 16; ++n) acc[n] = 0.f;

    for (int k = 0; k < DDIM; k += 4) {
        const float w0 = wcol[(k + 0) * DDIM];
        const float w1 = wcol[(k + 1) * DDIM];
        const float w2 = wcol[(k + 2) * DDIM];
        const float w3 = wcol[(k + 3) * DDIM];
        #pragma unroll
        for (int n = 0; n < 16; ++n) {
            float4 zv = *(const float4*)&zs[n * DDIM + k];
            acc[n] = fmaf(zv.x, w0, acc[n]);
            acc[n] = fmaf(zv.y, w1, acc[n]);
            acc[n] = fmaf(zv.z, w2, acc[n]);
            acc[n] = fmaf(zv.w, w3, acc[n]);
        }
    }

    float* outbase = (j < DDIM) ? (U + j) : (V + (j - DDIM));
    #pragma unroll
    for (int n = 0; n < 16; ++n) {
        int node = n0 + n;
        if (node < N) outbase[(size_t)node * DDIM] = acc[n];
    }
}

// ---------------------------------------------------------------------------
// Kernel 2: per-edge gather + relu + dot(W2).
// 32 lanes per edge; lane handles 4 consecutive d's via float4 (512 B
// contiguous per row gather, fully coalesced). Quarter-wave shuffle reduce.
// NOTE: harness delivers integer inputs as int32 (not the reference's int64).
// ---------------------------------------------------------------------------
__global__ __launch_bounds__(256) void edge_kernel(
    const int* __restrict__ ei,   // [2, E] int32 (harness converts int64->int32)
    const float* __restrict__ U, const float* __restrict__ V,
    const float* __restrict__ b1, const float* __restrict__ W2,
    const float* __restrict__ b2, float* __restrict__ out, int E)
{
    const int tid  = blockIdx.x * 256 + threadIdx.x;
    const int e    = tid >> 5;
    const int lane = tid & 31;
    if (e >= E) return;

    const int row = ei[e];
    const int col = ei[(size_t)E + e];

    const float4 u  = *(const float4*)(U + (size_t)row * DDIM + lane * 4);
    const float4 v  = *(const float4*)(V + (size_t)col * DDIM + lane * 4);
    const float4 bb = *(const float4*)(b1 + lane * 4);
    const float4 w  = *(const float4*)(W2 + lane * 4);

    const float t0 = fmaxf(u.x + v.x + bb.x, 0.f);
    const float t1 = fmaxf(u.y + v.y + bb.y, 0.f);
    const float t2 = fmaxf(u.z + v.z + bb.z, 0.f);
    const float t3 = fmaxf(u.w + v.w + bb.w, 0.f);
    float s = t0 * w.x + t1 * w.y + t2 * w.z + t3 * w.w;

    #pragma unroll
    for (int off = 16; off > 0; off >>= 1)
        s += __shfl_down(s, off, 32);

    if (lane == 0) out[e] = s + b2[0];
}

// ---------------------------------------------------------------------------
// Fallback (only if ws too small for U/V): fused per-edge GEMV. One 64-lane
// wave per edge; z-row reads are wave-uniform broadcasts, W1 reads coalesced.
// ---------------------------------------------------------------------------
__global__ __launch_bounds__(256) void edge_fused_fallback(
    const float* __restrict__ z, const int* __restrict__ ei,
    const float* __restrict__ W1, const float* __restrict__ b1,
    const float* __restrict__ W2, const float* __restrict__ b2,
    float* __restrict__ out, int N, int E)
{
    const int tid  = blockIdx.x * 256 + threadIdx.x;
    const int e    = tid >> 6;
    const int lane = tid & 63;
    if (e >= E) return;

    const int row = ei[e];
    const int col = ei[(size_t)E + e];
    const float* zr = z + (size_t)row * DDIM;
    const float* zc = z + (size_t)col * DDIM;

    float h0 = b1[lane];
    float h1 = b1[lane + 64];
    for (int k = 0; k < DDIM; ++k) {
        const float a = zr[k];
        const float b = zc[k];
        h0 = fmaf(a, W1[k * DDIM + lane],              h0);
        h0 = fmaf(b, W1[(DDIM + k) * DDIM + lane],     h0);
        h1 = fmaf(a, W1[k * DDIM + lane + 64],         h1);
        h1 = fmaf(b, W1[(DDIM + k) * DDIM + lane + 64], h1);
    }
    float s = fmaxf(h0, 0.f) * W2[lane] + fmaxf(h1, 0.f) * W2[lane + 64];
    #pragma unroll
    for (int off = 32; off > 0; off >>= 1)
        s += __shfl_down(s, off, 64);
    if (lane == 0) out[e] = s + b2[0];
}

extern "C" void kernel_launch(void* const* d_in, const int* in_sizes, int n_in,
                              void* d_out, int out_size, void* d_ws, size_t ws_size,
                              hipStream_t stream)
{
    const float* z  = (const float*)d_in[0];
    const int*   ei = (const int*)d_in[1];       // int32 per harness convention
    const float* W1 = (const float*)d_in[2];
    const float* b1 = (const float*)d_in[3];
    const float* W2 = (const float*)d_in[4];
    const float* b2 = (const float*)d_in[5];
    float*       out = (float*)d_out;

    const int N = in_sizes[0] / DDIM;
    const int E = in_sizes[1] / 2;

    const size_t uv_bytes = 2 * (size_t)N * DDIM * sizeof(float);
    if (ws_size >= uv_bytes) {
        float* U = (float*)d_ws;
        float* V = U + (size_t)N * DDIM;
        hipLaunchKernelGGL(precompute_uv, dim3((N + 15) / 16), dim3(256), 0, stream,
                           z, W1, U, V, N);
        hipLaunchKernelGGL(edge_kernel, dim3((E + 7) / 8), dim3(256), 0, stream,
                           ei, U, V, b1, W2, b2, out, E);
    } else {
        hipLaunchKernelGGL(edge_fused_fallback, dim3((E + 3) / 4), dim3(256), 0, stream,
                           z, ei, W1, b1, W2, b2, out, N, E);
    }
}

// Round 3
// 230.871 us; speedup vs baseline: 1.3904x; 1.3904x over previous
//
#include <hip/hip_runtime.h>

#define DDIM 128

typedef __bf16 bf16x8 __attribute__((ext_vector_type(8)));
typedef float  floatx4 __attribute__((ext_vector_type(4)));

__device__ inline unsigned short f2bf(float f) {      // RNE fp32 -> bf16 bits
    unsigned u = __builtin_bit_cast(unsigned, f);
    u += 0x7fffu + ((u >> 16) & 1u);
    return (unsigned short)(u >> 16);
}
__device__ inline float bf2f(unsigned short s) {
    unsigned u = ((unsigned)s) << 16;
    return __builtin_bit_cast(float, u);
}

// ---------------------------------------------------------------------------
// Kernel 1: [U|V] = z @ W_combined  via bf16 MFMA 16x16x32, fp32 accumulate.
//   W_combined[k][n] = (n<128) ? W1[k][n] : W1[128+k][n-128],  K=128, N=256.
// W is staged ONCE per block into LDS in B-fragment order:
//   WsF[(nt*4+ks)*64 + lane][0..7] = W_combined[ks*32 + (lane>>4)*8 + j][nt*16 + (lane&15)]
// so the compute-phase B read is a lane-contiguous conflict-free ds_read_b128.
// Block = 256 thr (4 waves); each wave owns 16 rows x 256 cols per chunk;
// grid-strides over 64-row chunks to amortize staging.
// A-frags come straight from global (each z element read once per chunk).
// ---------------------------------------------------------------------------
__global__ __launch_bounds__(256, 2) void precompute_uv_mfma(
    const float* __restrict__ z, const float* __restrict__ W1,
    const float* __restrict__ b1,
    unsigned short* __restrict__ U, unsigned short* __restrict__ V,
    int N, int nchunks)
{
    __shared__ unsigned short WsF[64 * 64 * 8];   // 64 KiB

    const int t    = threadIdx.x;
    const int lane = t & 63;
    const int w    = t >> 6;        // wave 0..3

    // ---- stage W fragments (once per block) ----
    {
        const int nlow = lane & 15;
        const int kq   = (lane >> 4) & 3;
        for (int i = 0; i < 16; ++i) {
            const int ntks = w + i * 4;          // 0..63, unique per (w,i)
            const int nt = ntks >> 2, ks = ntks & 3;
            const int n  = nt * 16 + nlow;
            const int kb = ks * 32 + kq * 8;
            unsigned short frag[8];
            #pragma unroll
            for (int j = 0; j < 8; ++j) {
                const int k = kb + j;
                const float v = (n < DDIM) ? W1[k * DDIM + n]
                                           : W1[(DDIM + k) * DDIM + (n - DDIM)];
                frag[j] = f2bf(v);
            }
            *(uint4*)&WsF[(ntks * 64 + lane) * 8] = *(const uint4*)frag;
        }
    }
    __syncthreads();

    const int mrow = lane & 15;     // A row / C col position
    const int quad = lane >> 4;

    for (int chunk = blockIdx.x; chunk < nchunks; chunk += gridDim.x) {
        const int m0 = chunk * 64 + w * 16;

        // A fragments: lane holds z[m0+mrow][ks*32 + quad*8 + j], j=0..7
        bf16x8 afrag[4];
        {
            int grow = m0 + mrow; if (grow > N - 1) grow = N - 1;   // clamp, predicated store
            const float* zrow = z + (size_t)grow * DDIM;
            #pragma unroll
            for (int ks = 0; ks < 4; ++ks) {
                const int k0 = ks * 32 + quad * 8;
                const float4 x0 = *(const float4*)(zrow + k0);
                const float4 x1 = *(const float4*)(zrow + k0 + 4);
                unsigned short a[8];
                a[0] = f2bf(x0.x); a[1] = f2bf(x0.y); a[2] = f2bf(x0.z); a[3] = f2bf(x0.w);
                a[4] = f2bf(x1.x); a[5] = f2bf(x1.y); a[6] = f2bf(x1.z); a[7] = f2bf(x1.w);
                afrag[ks] = __builtin_bit_cast(bf16x8, *(const uint4*)a);
            }
        }

        floatx4 acc[16];
        #pragma unroll
        for (int nt = 0; nt < 16; ++nt) acc[nt] = (floatx4){0.f, 0.f, 0.f, 0.f};

        #pragma unroll
        for (int ks = 0; ks < 4; ++ks) {
            #pragma unroll
            for (int nt = 0; nt < 16; ++nt) {
                const bf16x8 b = __builtin_bit_cast(bf16x8,
                    *(const uint4*)&WsF[((nt * 4 + ks) * 64 + lane) * 8]);
                acc[nt] = __builtin_amdgcn_mfma_f32_16x16x32_bf16(afrag[ks], b, acc[nt], 0, 0, 0);
            }
        }

        // C/D layout: col = lane&15, row = (lane>>4)*4 + r  [m89/m91 verified]
        #pragma unroll
        for (int nt = 0; nt < 16; ++nt) {
            const int col = nt * 16 + mrow;
            unsigned short* dst = (col < DDIM) ? (U + col) : (V + (col - DDIM));
            #pragma unroll
            for (int r = 0; r < 4; ++r) {
                const int grow = m0 + quad * 4 + r;
                if (grow < N) dst[(size_t)grow * DDIM] = f2bf(acc[nt][r]);
            }
        }
    }
}

// ---------------------------------------------------------------------------
// Kernel 2: per-edge gather (bf16 U/V) + b1 + relu + dot(W2) + b2.
// 16 lanes per edge; lane loads 8 bf16 (uint4, 16 B) from each of U[row],
// V[col] -> 256 B per row gather, coalesced. b1/W2 fragments preloaded.
// ---------------------------------------------------------------------------
__global__ __launch_bounds__(256) void edge_kernel_bf16(
    const int* __restrict__ ei,
    const unsigned short* __restrict__ U, const unsigned short* __restrict__ V,
    const float* __restrict__ b1, const float* __restrict__ W2,
    const float* __restrict__ b2, float* __restrict__ out, int E)
{
    const int t = threadIdx.x;
    const int p = t & 15;
    const int g = blockIdx.x * 16 + (t >> 4);

    float bb[8], ww[8];
    {
        const float4 b0 = *(const float4*)(b1 + p * 8);
        const float4 b4 = *(const float4*)(b1 + p * 8 + 4);
        const float4 w0 = *(const float4*)(W2 + p * 8);
        const float4 w4 = *(const float4*)(W2 + p * 8 + 4);
        bb[0]=b0.x; bb[1]=b0.y; bb[2]=b0.z; bb[3]=b0.w;
        bb[4]=b4.x; bb[5]=b4.y; bb[6]=b4.z; bb[7]=b4.w;
        ww[0]=w0.x; ww[1]=w0.y; ww[2]=w0.z; ww[3]=w0.w;
        ww[4]=w4.x; ww[5]=w4.y; ww[6]=w4.z; ww[7]=w4.w;
    }

    if (g >= E) return;

    const int row = ei[g];
    const int col = ei[(size_t)E + g];

    const uint4 uu = *(const uint4*)(U + (size_t)row * DDIM + p * 8);
    const uint4 vv = *(const uint4*)(V + (size_t)col * DDIM + p * 8);
    const unsigned short* us = (const unsigned short*)&uu;
    const unsigned short* vs = (const unsigned short*)&vv;

    float s = 0.f;
    #pragma unroll
    for (int j = 0; j < 8; ++j) {
        const float h = bf2f(us[j]) + bf2f(vs[j]) + bb[j];
        s = fmaf(fmaxf(h, 0.f), ww[j], s);
    }
    #pragma unroll
    for (int off = 8; off > 0; off >>= 1)
        s += __shfl_down(s, off, 16);

    if (p == 0) out[g] = s + b2[0];
}

// ---------------------------------------------------------------------------
// Fallback (ws too small): fused per-edge fp32 GEMV (known-correct path).
// ---------------------------------------------------------------------------
__global__ __launch_bounds__(256) void edge_fused_fallback(
    const float* __restrict__ z, const int* __restrict__ ei,
    const float* __restrict__ W1, const float* __restrict__ b1,
    const float* __restrict__ W2, const float* __restrict__ b2,
    float* __restrict__ out, int N, int E)
{
    const int tid  = blockIdx.x * 256 + threadIdx.x;
    const int e    = tid >> 6;
    const int lane = tid & 63;
    if (e >= E) return;

    const int row = ei[e];
    const int col = ei[(size_t)E + e];
    const float* zr = z + (size_t)row * DDIM;
    const float* zc = z + (size_t)col * DDIM;

    float h0 = b1[lane];
    float h1 = b1[lane + 64];
    for (int k = 0; k < DDIM; ++k) {
        const float a = zr[k];
        const float b = zc[k];
        h0 = fmaf(a, W1[k * DDIM + lane],               h0);
        h0 = fmaf(b, W1[(DDIM + k) * DDIM + lane],      h0);
        h1 = fmaf(a, W1[k * DDIM + lane + 64],          h1);
        h1 = fmaf(b, W1[(DDIM + k) * DDIM + lane + 64], h1);
    }
    float s = fmaxf(h0, 0.f) * W2[lane] + fmaxf(h1, 0.f) * W2[lane + 64];
    #pragma unroll
    for (int off = 32; off > 0; off >>= 1)
        s += __shfl_down(s, off, 64);
    if (lane == 0) out[e] = s + b2[0];
}

extern "C" void kernel_launch(void* const* d_in, const int* in_sizes, int n_in,
                              void* d_out, int out_size, void* d_ws, size_t ws_size,
                              hipStream_t stream)
{
    const float* z  = (const float*)d_in[0];
    const int*   ei = (const int*)d_in[1];       // int32 per harness convention
    const float* W1 = (const float*)d_in[2];
    const float* b1 = (const float*)d_in[3];
    const float* W2 = (const float*)d_in[4];
    const float* b2 = (const float*)d_in[5];
    float*       out = (float*)d_out;

    const int N = in_sizes[0] / DDIM;
    const int E = in_sizes[1] / 2;

    const size_t uv_bytes = 2 * (size_t)N * DDIM * sizeof(unsigned short);
    if (ws_size >= uv_bytes) {
        unsigned short* U = (unsigned short*)d_ws;
        unsigned short* V = U + (size_t)N * DDIM;
        const int nchunks = (N + 63) / 64;
        hipLaunchKernelGGL(precompute_uv_mfma, dim3(512), dim3(256), 0, stream,
                           z, W1, b1, U, V, N, nchunks);
        hipLaunchKernelGGL(edge_kernel_bf16, dim3((E + 15) / 16), dim3(256), 0, stream,
                           ei, U, V, b1, W2, b2, out, E);
    } else {
        hipLaunchKernelGGL(edge_fused_fallback, dim3((E + 3) / 4), dim3(256), 0, stream,
                           z, ei, W1, b1, W2, b2, out, N, E);
    }
}

// Round 4
// 173.473 us; speedup vs baseline: 1.8505x; 1.3309x over previous
//
#include <hip/hip_runtime.h>

#define DDIM 128

typedef __bf16 bf16x8 __attribute__((ext_vector_type(8)));
typedef float  floatx4 __attribute__((ext_vector_type(4)));

__device__ inline unsigned short f2bf(float f) {      // RNE fp32 -> bf16 bits
    unsigned u = __builtin_bit_cast(unsigned, f);
    u += 0x7fffu + ((u >> 16) & 1u);
    return (unsigned short)(u >> 16);
}
__device__ inline float bf2f(unsigned short s) {
    unsigned u = ((unsigned)s) << 16;
    return __builtin_bit_cast(float, u);
}

// ---------------------------------------------------------------------------
// Kernel 1: one N-half of [U|V] = z @ W_combined per block (bf16 MFMA 16x16x32).
//   half=0: U[n][j] = sum_k z[n][k]*W1[k][j]        (+ b1[j] folded in)
//   half=1: V[n][j] = sum_k z[n][k]*W1[128+k][j]
// W-half staged once per block into LDS in B-fragment order (32 KB).
// Epilogue: acc -> padded LDS tile (stride 132 ushorts; quad row offset
// 1056 B -> bank shifts {0,8,16,24}, conflict-free) -> contiguous 512 B/wave
// global stores. Fixes the 2x write amplification of the direct C-layout
// store (WRITE_SIZE was 105 MB for a 51.2 MB output).
// ---------------------------------------------------------------------------
#define EPI_STRIDE 132   // ushorts per row; 264 B: 8B-aligned rows, padded banks

__global__ __launch_bounds__(256) void precompute_uv_mfma(
    const float* __restrict__ z, const float* __restrict__ W1,
    const float* __restrict__ b1,
    unsigned short* __restrict__ U, unsigned short* __restrict__ V,
    int N, int nchunks)
{
    __shared__ unsigned short WsF[32 * 64 * 8];        // 32 KiB: B-frags
    __shared__ unsigned short epi[64 * EPI_STRIDE];    // ~16.9 KiB epilogue

    const int t    = threadIdx.x;
    const int lane = t & 63;
    const int w    = t >> 6;            // wave 0..3
    const int half = blockIdx.x;        // 0 -> U, 1 -> V
    unsigned short* __restrict__ dst = half ? V : U;
    const float* __restrict__ Wh = W1 + (size_t)half * DDIM * DDIM;

    // ---- stage W-half fragments (once per block) ----
    {
        const int nlow = lane & 15;
        const int kq   = (lane >> 4) & 3;
        #pragma unroll
        for (int i = 0; i < 8; ++i) {
            const int ntks = w + i * 4;              // 0..31
            const int nt = ntks >> 2, ks = ntks & 3;
            const int n  = nt * 16 + nlow;
            const int kb = ks * 32 + kq * 8;
            unsigned short frag[8];
            #pragma unroll
            for (int j = 0; j < 8; ++j)
                frag[j] = f2bf(Wh[(kb + j) * DDIM + n]);
            *(uint4*)&WsF[(ntks * 64 + lane) * 8] = *(const uint4*)frag;
        }
    }
    __syncthreads();

    const int mrow = lane & 15;
    const int quad = lane >> 4;

    for (int chunk = blockIdx.y; chunk < nchunks; chunk += gridDim.y) {
        const int m0 = chunk * 64 + w * 16;

        // A fragments: lane holds z[m0+mrow][ks*32 + quad*8 + j]
        bf16x8 afrag[4];
        {
            int grow = m0 + mrow; if (grow > N - 1) grow = N - 1;
            const float* zrow = z + (size_t)grow * DDIM;
            #pragma unroll
            for (int ks = 0; ks < 4; ++ks) {
                const int k0 = ks * 32 + quad * 8;
                const float4 x0 = *(const float4*)(zrow + k0);
                const float4 x1 = *(const float4*)(zrow + k0 + 4);
                unsigned short a[8];
                a[0] = f2bf(x0.x); a[1] = f2bf(x0.y); a[2] = f2bf(x0.z); a[3] = f2bf(x0.w);
                a[4] = f2bf(x1.x); a[5] = f2bf(x1.y); a[6] = f2bf(x1.z); a[7] = f2bf(x1.w);
                afrag[ks] = __builtin_bit_cast(bf16x8, *(const uint4*)a);
            }
        }

        floatx4 acc[8];
        #pragma unroll
        for (int nt = 0; nt < 8; ++nt) acc[nt] = (floatx4){0.f, 0.f, 0.f, 0.f};

        #pragma unroll
        for (int ks = 0; ks < 4; ++ks) {
            #pragma unroll
            for (int nt = 0; nt < 8; ++nt) {
                const bf16x8 b = __builtin_bit_cast(bf16x8,
                    *(const uint4*)&WsF[((nt * 4 + ks) * 64 + lane) * 8]);
                acc[nt] = __builtin_amdgcn_mfma_f32_16x16x32_bf16(afrag[ks], b, acc[nt], 0, 0, 0);
            }
        }

        // ---- epilogue: C-layout (col=lane&15, row=quad*4+r) -> padded LDS ----
        #pragma unroll
        for (int nt = 0; nt < 8; ++nt) {
            const int col  = nt * 16 + mrow;
            const float bias = (half == 0) ? b1[col] : 0.f;
            #pragma unroll
            for (int r = 0; r < 4; ++r) {
                const int lrow = w * 16 + quad * 4 + r;
                epi[lrow * EPI_STRIDE + col] = f2bf(acc[nt][r] + bias);
            }
        }
        __builtin_amdgcn_s_waitcnt(0);   // wave-local LDS ordering (lgkmcnt 0)

        // ---- wave-local read-out: 512 B contiguous per store inst ----
        {
            const int cg = lane & 31;            // 32 col-groups of 4 ushorts
            const int r2 = lane >> 5;            // 0..1
            #pragma unroll
            for (int it = 0; it < 8; ++it) {
                const int lr   = r2 + it * 2;            // 0..15 within wave
                const int lrow = w * 16 + lr;
                const uint2 dat = *(const uint2*)&epi[lrow * EPI_STRIDE + cg * 4];
                const int grow = chunk * 64 + lrow;
                if (grow < N)
                    *(uint2*)&dst[(size_t)grow * DDIM + cg * 4] = dat;
            }
        }
        __syncthreads();   // protect epi reuse across grid-stride iterations
    }
}

// ---------------------------------------------------------------------------
// Kernel 2: per-edge gather (bf16 U/V, b1 pre-folded into U) + relu + dot(W2).
// 16 lanes per edge; lane loads 8 bf16 (16 B) from each of U[row], V[col].
// ---------------------------------------------------------------------------
__global__ __launch_bounds__(256) void edge_kernel_bf16(
    const int* __restrict__ ei,
    const unsigned short* __restrict__ U, const unsigned short* __restrict__ V,
    const float* __restrict__ W2, const float* __restrict__ b2,
    float* __restrict__ out, int E)
{
    const int t = threadIdx.x;
    const int p = t & 15;
    const int g = blockIdx.x * 16 + (t >> 4);

    float ww[8];
    {
        const float4 w0 = *(const float4*)(W2 + p * 8);
        const float4 w4 = *(const float4*)(W2 + p * 8 + 4);
        ww[0]=w0.x; ww[1]=w0.y; ww[2]=w0.z; ww[3]=w0.w;
        ww[4]=w4.x; ww[5]=w4.y; ww[6]=w4.z; ww[7]=w4.w;
    }

    if (g >= E) return;

    const int row = ei[g];
    const int col = ei[(size_t)E + g];

    const uint4 uu = *(const uint4*)(U + (size_t)row * DDIM + p * 8);
    const uint4 vv = *(const uint4*)(V + (size_t)col * DDIM + p * 8);
    const unsigned short* us = (const unsigned short*)&uu;
    const unsigned short* vs = (const unsigned short*)&vv;

    float s = 0.f;
    #pragma unroll
    for (int j = 0; j < 8; ++j) {
        const float h = bf2f(us[j]) + bf2f(vs[j]);
        s = fmaf(fmaxf(h, 0.f), ww[j], s);
    }
    #pragma unroll
    for (int off = 8; off > 0; off >>= 1)
        s += __shfl_down(s, off, 16);

    if (p == 0) out[g] = s + b2[0];
}

// ---------------------------------------------------------------------------
// Fallback (ws too small): fused per-edge fp32 GEMV (known-correct path).
// ---------------------------------------------------------------------------
__global__ __launch_bounds__(256) void edge_fused_fallback(
    const float* __restrict__ z, const int* __restrict__ ei,
    const float* __restrict__ W1, const float* __restrict__ b1,
    const float* __restrict__ W2, const float* __restrict__ b2,
    float* __restrict__ out, int N, int E)
{
    const int tid  = blockIdx.x * 256 + threadIdx.x;
    const int e    = tid >> 6;
    const int lane = tid & 63;
    if (e >= E) return;

    const int row = ei[e];
    const int col = ei[(size_t)E + e];
    const float* zr = z + (size_t)row * DDIM;
    const float* zc = z + (size_t)col * DDIM;

    float h0 = b1[lane];
    float h1 = b1[lane + 64];
    for (int k = 0; k < DDIM; ++k) {
        const float a = zr[k];
        const float b = zc[k];
        h0 = fmaf(a, W1[k * DDIM + lane],               h0);
        h0 = fmaf(b, W1[(DDIM + k) * DDIM + lane],      h0);
        h1 = fmaf(a, W1[k * DDIM + lane + 64],          h1);
        h1 = fmaf(b, W1[(DDIM + k) * DDIM + lane + 64], h1);
    }
    float s = fmaxf(h0, 0.f) * W2[lane] + fmaxf(h1, 0.f) * W2[lane + 64];
    #pragma unroll
    for (int off = 32; off > 0; off >>= 1)
        s += __shfl_down(s, off, 64);
    if (lane == 0) out[e] = s + b2[0];
}

extern "C" void kernel_launch(void* const* d_in, const int* in_sizes, int n_in,
                              void* d_out, int out_size, void* d_ws, size_t ws_size,
                              hipStream_t stream)
{
    const float* z  = (const float*)d_in[0];
    const int*   ei = (const int*)d_in[1];       // int32 per harness convention
    const float* W1 = (const float*)d_in[2];
    const float* b1 = (const float*)d_in[3];
    const float* W2 = (const float*)d_in[4];
    const float* b2 = (const float*)d_in[5];
    float*       out = (float*)d_out;

    const int N = in_sizes[0] / DDIM;
    const int E = in_sizes[1] / 2;

    const size_t uv_bytes = 2 * (size_t)N * DDIM * sizeof(unsigned short);
    if (ws_size >= uv_bytes) {
        unsigned short* U = (unsigned short*)d_ws;
        unsigned short* V = U + (size_t)N * DDIM;
        const int nchunks = (N + 63) / 64;
        const int ychunks = (nchunks + 1) / 2;   // 2 chunks per block
        hipLaunchKernelGGL(precompute_uv_mfma, dim3(2, ychunks), dim3(256), 0, stream,
                           z, W1, b1, U, V, N, nchunks);
        hipLaunchKernelGGL(edge_kernel_bf16, dim3((E + 15) / 16), dim3(256), 0, stream,
                           ei, U, V, W2, b2, out, E);
    } else {
        hipLaunchKernelGGL(edge_fused_fallback, dim3((E + 3) / 4), dim3(256), 0, stream,
                           z, ei, W1, b1, W2, b2, out, N, E);
    }
}

// Round 5
// 168.309 us; speedup vs baseline: 1.9072x; 1.0307x over previous
//
#include <hip/hip_runtime.h>

#define DDIM 128

typedef __bf16 bf16x8 __attribute__((ext_vector_type(8)));
typedef float  floatx4 __attribute__((ext_vector_type(4)));

__device__ inline unsigned short f2bf(float f) {      // RNE fp32 -> bf16 bits
    unsigned u = __builtin_bit_cast(unsigned, f);
    u += 0x7fffu + ((u >> 16) & 1u);
    return (unsigned short)(u >> 16);
}
__device__ inline float bf2f(unsigned short s) {
    unsigned u = ((unsigned)s) << 16;
    return __builtin_bit_cast(float, u);
}

// ---------------------------------------------------------------------------
// Kernel 1: one N-half of [U|V] = z @ W_combined per block (bf16 MFMA 16x16x32).
//   half=0: U[n][j] = sum_k z[n][k]*W1[k][j]  (+ b1[j] folded in)
//   half=1: V[n][j] = sum_k z[n][k]*W1[128+k][j]
// W-half staged once per block in LDS B-fragment order (32 KB). Epilogue goes
// through a padded LDS tile (conflict-free) then 512 B-contiguous stores
// (fixes 2x write amplification of direct C-layout stores).
// Grid = (2 halves, 384): 768 blocks = exactly 3 blocks/CU resident (49.4 KB
// LDS each) -> single dispatch generation; each block grid-strides ~5 chunks.
// ---------------------------------------------------------------------------
#define EPI_STRIDE 132   // ushorts per row; 264 B rows: 8B-aligned, bank-shifted

__global__ __launch_bounds__(256) void precompute_uv_mfma(
    const float* __restrict__ z, const float* __restrict__ W1,
    const float* __restrict__ b1,
    unsigned short* __restrict__ U, unsigned short* __restrict__ V,
    int N, int nchunks)
{
    __shared__ unsigned short WsF[32 * 64 * 8];        // 32 KiB: B-frags
    __shared__ unsigned short epi[64 * EPI_STRIDE];    // ~16.9 KiB epilogue

    const int t    = threadIdx.x;
    const int lane = t & 63;
    const int w    = t >> 6;            // wave 0..3
    const int half = blockIdx.x;        // 0 -> U, 1 -> V
    unsigned short* __restrict__ dst = half ? V : U;
    const float* __restrict__ Wh = W1 + (size_t)half * DDIM * DDIM;

    // ---- stage W-half fragments (once per block) ----
    {
        const int nlow = lane & 15;
        const int kq   = (lane >> 4) & 3;
        #pragma unroll
        for (int i = 0; i < 8; ++i) {
            const int ntks = w + i * 4;              // 0..31
            const int nt = ntks >> 2, ks = ntks & 3;
            const int n  = nt * 16 + nlow;
            const int kb = ks * 32 + kq * 8;
            unsigned short frag[8];
            #pragma unroll
            for (int j = 0; j < 8; ++j)
                frag[j] = f2bf(Wh[(kb + j) * DDIM + n]);
            *(uint4*)&WsF[(ntks * 64 + lane) * 8] = *(const uint4*)frag;
        }
    }
    __syncthreads();

    const int mrow = lane & 15;
    const int quad = lane >> 4;

    for (int chunk = blockIdx.y; chunk < nchunks; chunk += gridDim.y) {
        const int m0 = chunk * 64 + w * 16;

        // A fragments: lane holds z[m0+mrow][ks*32 + quad*8 + j]
        bf16x8 afrag[4];
        {
            int grow = m0 + mrow; if (grow > N - 1) grow = N - 1;
            const float* zrow = z + (size_t)grow * DDIM;
            #pragma unroll
            for (int ks = 0; ks < 4; ++ks) {
                const int k0 = ks * 32 + quad * 8;
                const float4 x0 = *(const float4*)(zrow + k0);
                const float4 x1 = *(const float4*)(zrow + k0 + 4);
                unsigned short a[8];
                a[0] = f2bf(x0.x); a[1] = f2bf(x0.y); a[2] = f2bf(x0.z); a[3] = f2bf(x0.w);
                a[4] = f2bf(x1.x); a[5] = f2bf(x1.y); a[6] = f2bf(x1.z); a[7] = f2bf(x1.w);
                afrag[ks] = __builtin_bit_cast(bf16x8, *(const uint4*)a);
            }
        }

        floatx4 acc[8];
        #pragma unroll
        for (int nt = 0; nt < 8; ++nt) acc[nt] = (floatx4){0.f, 0.f, 0.f, 0.f};

        #pragma unroll
        for (int ks = 0; ks < 4; ++ks) {
            #pragma unroll
            for (int nt = 0; nt < 8; ++nt) {
                const bf16x8 b = __builtin_bit_cast(bf16x8,
                    *(const uint4*)&WsF[((nt * 4 + ks) * 64 + lane) * 8]);
                acc[nt] = __builtin_amdgcn_mfma_f32_16x16x32_bf16(afrag[ks], b, acc[nt], 0, 0, 0);
            }
        }

        // ---- epilogue: C-layout (col=lane&15, row=quad*4+r) -> padded LDS ----
        #pragma unroll
        for (int nt = 0; nt < 8; ++nt) {
            const int col  = nt * 16 + mrow;
            const float bias = (half == 0) ? b1[col] : 0.f;
            #pragma unroll
            for (int r = 0; r < 4; ++r) {
                const int lrow = w * 16 + quad * 4 + r;
                epi[lrow * EPI_STRIDE + col] = f2bf(acc[nt][r] + bias);
            }
        }
        __builtin_amdgcn_s_waitcnt(0);   // drain LDS writes (wave-local region)

        // ---- wave-local read-out: 512 B contiguous per store inst ----
        {
            const int cg = lane & 31;            // 32 col-groups of 4 ushorts
            const int r2 = lane >> 5;            // 0..1
            #pragma unroll
            for (int it = 0; it < 8; ++it) {
                const int lr   = r2 + it * 2;            // 0..15 within wave
                const int lrow = w * 16 + lr;
                const uint2 dat = *(const uint2*)&epi[lrow * EPI_STRIDE + cg * 4];
                const int grow = chunk * 64 + lrow;
                if (grow < N)
                    *(uint2*)&dst[(size_t)grow * DDIM + cg * 4] = dat;
            }
        }
        __syncthreads();   // protect epi reuse across grid-stride iterations
    }
}

// ---------------------------------------------------------------------------
// Kernel 2: per-edge gather (bf16 U/V, b1 pre-folded into U) + relu + dot(W2).
// 16 lanes per group, 4 edges per group: 8 outstanding 16 B gathers + 1 int4
// index load per thread (deep VMEM queue for random-access BW).
// ---------------------------------------------------------------------------
__global__ __launch_bounds__(256) void edge_kernel_bf16(
    const int* __restrict__ ei,
    const unsigned short* __restrict__ U, const unsigned short* __restrict__ V,
    const float* __restrict__ W2, const float* __restrict__ b2,
    float* __restrict__ out, int E)
{
    const int t  = threadIdx.x;
    const int p  = t & 15;
    const int g0 = (blockIdx.x * 16 + (t >> 4)) * 4;   // first of 4 edges

    float ww[8];
    {
        const float4 w0 = *(const float4*)(W2 + p * 8);
        const float4 w4 = *(const float4*)(W2 + p * 8 + 4);
        ww[0]=w0.x; ww[1]=w0.y; ww[2]=w0.z; ww[3]=w0.w;
        ww[4]=w4.x; ww[5]=w4.y; ww[6]=w4.z; ww[7]=w4.w;
    }

    if (g0 >= E) return;

    int rows[4], cols[4];
    if (g0 + 3 < E) {
        const int4 r4 = *(const int4*)(ei + g0);
        const int4 c4 = *(const int4*)(ei + (size_t)E + g0);
        rows[0]=r4.x; rows[1]=r4.y; rows[2]=r4.z; rows[3]=r4.w;
        cols[0]=c4.x; cols[1]=c4.y; cols[2]=c4.z; cols[3]=c4.w;
    } else {
        #pragma unroll
        for (int i = 0; i < 4; ++i) {
            const int gi = (g0 + i < E) ? (g0 + i) : (E - 1);
            rows[i] = ei[gi];
            cols[i] = ei[(size_t)E + gi];
        }
    }

    uint4 uu[4], vv[4];
    #pragma unroll
    for (int i = 0; i < 4; ++i)
        uu[i] = *(const uint4*)(U + (size_t)rows[i] * DDIM + p * 8);
    #pragma unroll
    for (int i = 0; i < 4; ++i)
        vv[i] = *(const uint4*)(V + (size_t)cols[i] * DDIM + p * 8);

    const float bias = b2[0];

    #pragma unroll
    for (int i = 0; i < 4; ++i) {
        const unsigned short* us = (const unsigned short*)&uu[i];
        const unsigned short* vs = (const unsigned short*)&vv[i];
        float s = 0.f;
        #pragma unroll
        for (int j = 0; j < 8; ++j) {
            const float h = bf2f(us[j]) + bf2f(vs[j]);
            s = fmaf(fmaxf(h, 0.f), ww[j], s);
        }
        #pragma unroll
        for (int off = 8; off > 0; off >>= 1)
            s += __shfl_down(s, off, 16);
        if (p == 0 && g0 + i < E) out[g0 + i] = s + bias;
    }
}

// ---------------------------------------------------------------------------
// Fallback (ws too small): fused per-edge fp32 GEMV (known-correct path).
// ---------------------------------------------------------------------------
__global__ __launch_bounds__(256) void edge_fused_fallback(
    const float* __restrict__ z, const int* __restrict__ ei,
    const float* __restrict__ W1, const float* __restrict__ b1,
    const float* __restrict__ W2, const float* __restrict__ b2,
    float* __restrict__ out, int N, int E)
{
    const int tid  = blockIdx.x * 256 + threadIdx.x;
    const int e    = tid >> 6;
    const int lane = tid & 63;
    if (e >= E) return;

    const int row = ei[e];
    const int col = ei[(size_t)E + e];
    const float* zr = z + (size_t)row * DDIM;
    const float* zc = z + (size_t)col * DDIM;

    float h0 = b1[lane];
    float h1 = b1[lane + 64];
    for (int k = 0; k < DDIM; ++k) {
        const float a = zr[k];
        const float b = zc[k];
        h0 = fmaf(a, W1[k * DDIM + lane],               h0);
        h0 = fmaf(b, W1[(DDIM + k) * DDIM + lane],      h0);
        h1 = fmaf(a, W1[k * DDIM + lane + 64],          h1);
        h1 = fmaf(b, W1[(DDIM + k) * DDIM + lane + 64], h1);
    }
    float s = fmaxf(h0, 0.f) * W2[lane] + fmaxf(h1, 0.f) * W2[lane + 64];
    #pragma unroll
    for (int off = 32; off > 0; off >>= 1)
        s += __shfl_down(s, off, 64);
    if (lane == 0) out[e] = s + b2[0];
}

extern "C" void kernel_launch(void* const* d_in, const int* in_sizes, int n_in,
                              void* d_out, int out_size, void* d_ws, size_t ws_size,
                              hipStream_t stream)
{
    const float* z  = (const float*)d_in[0];
    const int*   ei = (const int*)d_in[1];       // int32 per harness convention
    const float* W1 = (const float*)d_in[2];
    const float* b1 = (const float*)d_in[3];
    const float* W2 = (const float*)d_in[4];
    const float* b2 = (const float*)d_in[5];
    float*       out = (float*)d_out;

    const int N = in_sizes[0] / DDIM;
    const int E = in_sizes[1] / 2;

    const size_t uv_bytes = 2 * (size_t)N * DDIM * sizeof(unsigned short);
    if (ws_size >= uv_bytes) {
        unsigned short* U = (unsigned short*)d_ws;
        unsigned short* V = U + (size_t)N * DDIM;
        const int nchunks = (N + 63) / 64;
        // 768 blocks = 3 blocks/CU x 256 CUs: fully resident, one generation.
        hipLaunchKernelGGL(precompute_uv_mfma, dim3(2, 384), dim3(256), 0, stream,
                           z, W1, b1, U, V, N, nchunks);
        hipLaunchKernelGGL(edge_kernel_bf16, dim3((E + 63) / 64), dim3(256), 0, stream,
                           ei, U, V, W2, b2, out, E);
    } else {
        hipLaunchKernelGGL(edge_fused_fallback, dim3((E + 3) / 4), dim3(256), 0, stream,
                           z, ei, W1, b1, W2, b2, out, N, E);
    }
}

// Round 6
// 140.784 us; speedup vs baseline: 2.2801x; 1.1955x over previous
//
#include <hip/hip_runtime.h>

#define DDIM 128

typedef __bf16 bf16x8 __attribute__((ext_vector_type(8)));
typedef float  floatx4 __attribute__((ext_vector_type(4)));

__device__ inline unsigned short f2bf(float f) {      // RNE fp32 -> bf16 bits
    unsigned u = __builtin_bit_cast(unsigned, f);
    u += 0x7fffu + ((u >> 16) & 1u);
    return (unsigned short)(u >> 16);
}

// ---------------------------------------------------------------------------
// Kernel 1: one N-half of [U|V] = z @ W_combined per block (bf16 MFMA 16x16x32),
// output quantized to int8 with a per-node fp32 scale (traffic halving for the
// edge-gather phase; error budget analyzed: ~0.03 absmax vs 0.066 threshold).
//   half=0: U[n][:] = row n of z@W1[:128] + b1   -> U8 + u_scale
//   half=1: V[n][:] = row n of z@W1[128:]        -> V8 + v_scale
// W-half staged once per block in LDS B-fragment order (32 KB).
// Epilogue: rowmax via 16-lane shfl_xor (C-layout: row lives in one contiguous
// 16-lane group), quantize, pack 8 B/lane, store via column-PERMUTED LDS tile
//   col' = (col&15)*8 + (col>>4)
// so LDS writes are single ds_write_b64 and global stores are contiguous
// 128 B rows. The edge kernel un-permutes by indexing W2[j*16+p].
// ---------------------------------------------------------------------------
#define EPI_B 136   // bytes per row in epilogue tile (128 + 8 pad: bank stagger)

__global__ __launch_bounds__(256) void precompute_uv_mfma_q8(
    const float* __restrict__ z, const float* __restrict__ W1,
    const float* __restrict__ b1,
    signed char* __restrict__ U8, signed char* __restrict__ V8,
    float* __restrict__ u_scale, float* __restrict__ v_scale,
    int N, int nchunks)
{
    __shared__ unsigned short WsF[32 * 64 * 8];                      // 32 KiB
    __shared__ __attribute__((aligned(16))) unsigned char epi[64 * EPI_B];

    const int t    = threadIdx.x;
    const int lane = t & 63;
    const int w    = t >> 6;            // wave 0..3
    const int half = blockIdx.x;        // 0 -> U, 1 -> V
    signed char* __restrict__ dst8 = half ? V8 : U8;
    float*       __restrict__ dscl = half ? v_scale : u_scale;
    const float* __restrict__ Wh   = W1 + (size_t)half * DDIM * DDIM;

    // ---- stage W-half fragments (once per block) ----
    {
        const int nlow = lane & 15;
        const int kq   = (lane >> 4) & 3;
        #pragma unroll
        for (int i = 0; i < 8; ++i) {
            const int ntks = w + i * 4;              // 0..31
            const int nt = ntks >> 2, ks = ntks & 3;
            const int n  = nt * 16 + nlow;
            const int kb = ks * 32 + kq * 8;
            unsigned short frag[8];
            #pragma unroll
            for (int j = 0; j < 8; ++j)
                frag[j] = f2bf(Wh[(kb + j) * DDIM + n]);
            *(uint4*)&WsF[(ntks * 64 + lane) * 8] = *(const uint4*)frag;
        }
    }
    __syncthreads();

    const int mrow = lane & 15;    // C/D col within 16-tile
    const int quad = lane >> 4;    // C/D row group

    // bias per nt (col = nt*16 + mrow); b1 only applies to the U half
    float bval[8];
    #pragma unroll
    for (int nt = 0; nt < 8; ++nt)
        bval[nt] = (half == 0) ? b1[nt * 16 + mrow] : 0.f;

    for (int chunk = blockIdx.y; chunk < nchunks; chunk += gridDim.y) {
        const int m0 = chunk * 64 + w * 16;

        // A fragments: lane holds z[m0+mrow][ks*32 + quad*8 + j]
        bf16x8 afrag[4];
        {
            int grow = m0 + mrow; if (grow > N - 1) grow = N - 1;
            const float* zrow = z + (size_t)grow * DDIM;
            #pragma unroll
            for (int ks = 0; ks < 4; ++ks) {
                const int k0 = ks * 32 + quad * 8;
                const float4 x0 = *(const float4*)(zrow + k0);
                const float4 x1 = *(const float4*)(zrow + k0 + 4);
                unsigned short a[8];
                a[0] = f2bf(x0.x); a[1] = f2bf(x0.y); a[2] = f2bf(x0.z); a[3] = f2bf(x0.w);
                a[4] = f2bf(x1.x); a[5] = f2bf(x1.y); a[6] = f2bf(x1.z); a[7] = f2bf(x1.w);
                afrag[ks] = __builtin_bit_cast(bf16x8, *(const uint4*)a);
            }
        }

        floatx4 acc[8];
        #pragma unroll
        for (int nt = 0; nt < 8; ++nt) acc[nt] = (floatx4){0.f, 0.f, 0.f, 0.f};

        #pragma unroll
        for (int ks = 0; ks < 4; ++ks) {
            #pragma unroll
            for (int nt = 0; nt < 8; ++nt) {
                const bf16x8 b = __builtin_bit_cast(bf16x8,
                    *(const uint4*)&WsF[((nt * 4 + ks) * 64 + lane) * 8]);
                acc[nt] = __builtin_amdgcn_mfma_f32_16x16x32_bf16(afrag[ks], b, acc[nt], 0, 0, 0);
            }
        }

        // ---- quantize epilogue ----
        // C-layout: value (nt,r) -> row quad*4+r (local), col nt*16+mrow.
        #pragma unroll
        for (int r = 0; r < 4; ++r) {
            float mx = 0.f;
            #pragma unroll
            for (int nt = 0; nt < 8; ++nt)
                mx = fmaxf(mx, fabsf(acc[nt][r] + bval[nt]));
            // row lives across the 16 lanes of this quad-group
            #pragma unroll
            for (int m = 1; m < 16; m <<= 1)
                mx = fmaxf(mx, __shfl_xor(mx, m, 16));
            mx = fmaxf(mx, 1e-20f);
            const float inv = 127.f / mx;

            unsigned char bytes[8];
            #pragma unroll
            for (int nt = 0; nt < 8; ++nt) {
                const float v = (acc[nt][r] + bval[nt]) * inv;
                const int q = (int)rintf(v);        // in [-127,127] by construction
                bytes[nt] = (unsigned char)(q & 0xff);
            }
            const int lrow = w * 16 + quad * 4 + r;
            // permuted col': mrow*8 + nt  -> contiguous 8 bytes, one b64 write
            *(unsigned long long*)&epi[lrow * EPI_B + mrow * 8] =
                *(const unsigned long long*)bytes;

            if (mrow == 0) {
                const int grow = chunk * 64 + lrow;
                if (grow < N) dscl[grow] = mx * (1.f / 127.f);
            }
        }
        __builtin_amdgcn_s_waitcnt(0);   // drain LDS writes (wave-local rows)

        // ---- read-out: 16 rows x 128 B, contiguous global stores ----
        {
            const int cg = lane & 15;    // 16 col-groups of 8 bytes
            const int r2 = lane >> 4;    // 4 rows per store inst
            #pragma unroll
            for (int it = 0; it < 4; ++it) {
                const int lr   = it * 4 + r2;
                const int lrow = w * 16 + lr;
                const uint2 dat = *(const uint2*)&epi[lrow * EPI_B + cg * 8];
                const int grow = chunk * 64 + lrow;
                if (grow < N)
                    *(uint2*)&dst8[(size_t)grow * DDIM + cg * 8] = dat;
            }
        }
        // epi rows are per-wave private; no __syncthreads needed across chunks
    }
}

// ---------------------------------------------------------------------------
// Kernel 2: per-edge gather (int8 U/V + per-node scales) + relu + dot(W2).
// 16 lanes per group, 4 edges per group. Lane p's 8 bytes are permuted cols
// j*16+p, so ww[j] = W2[j*16+p].
// ---------------------------------------------------------------------------
__global__ __launch_bounds__(256) void edge_kernel_i8(
    const int* __restrict__ ei,
    const signed char* __restrict__ U8, const signed char* __restrict__ V8,
    const float* __restrict__ u_scale, const float* __restrict__ v_scale,
    const float* __restrict__ W2, const float* __restrict__ b2,
    float* __restrict__ out, int E)
{
    const int t  = threadIdx.x;
    const int p  = t & 15;
    const int g0 = (blockIdx.x * 16 + (t >> 4)) * 4;   // first of 4 edges

    float ww[8];
    #pragma unroll
    for (int j = 0; j < 8; ++j) ww[j] = W2[j * 16 + p];

    if (g0 >= E) return;

    int rows[4], cols[4];
    if (g0 + 3 < E) {
        const int4 r4 = *(const int4*)(ei + g0);
        const int4 c4 = *(const int4*)(ei + (size_t)E + g0);
        rows[0]=r4.x; rows[1]=r4.y; rows[2]=r4.z; rows[3]=r4.w;
        cols[0]=c4.x; cols[1]=c4.y; cols[2]=c4.z; cols[3]=c4.w;
    } else {
        #pragma unroll
        for (int i = 0; i < 4; ++i) {
            const int gi = (g0 + i < E) ? (g0 + i) : (E - 1);
            rows[i] = ei[gi];
            cols[i] = ei[(size_t)E + gi];
        }
    }

    uint2 uu[4], vv[4];
    #pragma unroll
    for (int i = 0; i < 4; ++i)
        uu[i] = *(const uint2*)(U8 + (size_t)rows[i] * DDIM + p * 8);
    #pragma unroll
    for (int i = 0; i < 4; ++i)
        vv[i] = *(const uint2*)(V8 + (size_t)cols[i] * DDIM + p * 8);

    float su[4], sv[4];
    #pragma unroll
    for (int i = 0; i < 4; ++i) { su[i] = u_scale[rows[i]]; sv[i] = v_scale[cols[i]]; }

    const float bias = b2[0];

    #pragma unroll
    for (int i = 0; i < 4; ++i) {
        const signed char* us = (const signed char*)&uu[i];
        const signed char* vs = (const signed char*)&vv[i];
        float s = 0.f;
        #pragma unroll
        for (int j = 0; j < 8; ++j) {
            const float h = fmaf(sv[i], (float)vs[j], su[i] * (float)us[j]);
            s = fmaf(fmaxf(h, 0.f), ww[j], s);
        }
        #pragma unroll
        for (int off = 8; off > 0; off >>= 1)
            s += __shfl_down(s, off, 16);
        if (p == 0 && g0 + i < E) out[g0 + i] = s + bias;
    }
}

// ---------------------------------------------------------------------------
// Fallback (ws too small): fused per-edge fp32 GEMV (known-correct path).
// ---------------------------------------------------------------------------
__global__ __launch_bounds__(256) void edge_fused_fallback(
    const float* __restrict__ z, const int* __restrict__ ei,
    const float* __restrict__ W1, const float* __restrict__ b1,
    const float* __restrict__ W2, const float* __restrict__ b2,
    float* __restrict__ out, int N, int E)
{
    const int tid  = blockIdx.x * 256 + threadIdx.x;
    const int e    = tid >> 6;
    const int lane = tid & 63;
    if (e >= E) return;

    const int row = ei[e];
    const int col = ei[(size_t)E + e];
    const float* zr = z + (size_t)row * DDIM;
    const float* zc = z + (size_t)col * DDIM;

    float h0 = b1[lane];
    float h1 = b1[lane + 64];
    for (int k = 0; k < DDIM; ++k) {
        const float a = zr[k];
        const float b = zc[k];
        h0 = fmaf(a, W1[k * DDIM + lane],               h0);
        h0 = fmaf(b, W1[(DDIM + k) * DDIM + lane],      h0);
        h1 = fmaf(a, W1[k * DDIM + lane + 64],          h1);
        h1 = fmaf(b, W1[(DDIM + k) * DDIM + lane + 64], h1);
    }
    float s = fmaxf(h0, 0.f) * W2[lane] + fmaxf(h1, 0.f) * W2[lane + 64];
    #pragma unroll
    for (int off = 32; off > 0; off >>= 1)
        s += __shfl_down(s, off, 64);
    if (lane == 0) out[e] = s + b2[0];
}

extern "C" void kernel_launch(void* const* d_in, const int* in_sizes, int n_in,
                              void* d_out, int out_size, void* d_ws, size_t ws_size,
                              hipStream_t stream)
{
    const float* z  = (const float*)d_in[0];
    const int*   ei = (const int*)d_in[1];       // int32 per harness convention
    const float* W1 = (const float*)d_in[2];
    const float* b1 = (const float*)d_in[3];
    const float* W2 = (const float*)d_in[4];
    const float* b2 = (const float*)d_in[5];
    float*       out = (float*)d_out;

    const int N = in_sizes[0] / DDIM;
    const int E = in_sizes[1] / 2;

    const size_t n128 = (size_t)N * DDIM;
    const size_t need = 2 * n128 + 2 * (size_t)N * sizeof(float) + 256;
    if (ws_size >= need) {
        signed char* U8 = (signed char*)d_ws;
        signed char* V8 = U8 + n128;
        float* usc = (float*)(((size_t)(V8 + n128) + 255) & ~(size_t)255);
        float* vsc = usc + N;
        const int nchunks = (N + 63) / 64;
        // 768 blocks = 3 blocks/CU x 256 CUs resident; grid-stride chunks.
        hipLaunchKernelGGL(precompute_uv_mfma_q8, dim3(2, 384), dim3(256), 0, stream,
                           z, W1, b1, U8, V8, usc, vsc, N, nchunks);
        hipLaunchKernelGGL(edge_kernel_i8, dim3((E + 63) / 64), dim3(256), 0, stream,
                           ei, U8, V8, usc, vsc, W2, b2, out, E);
    } else {
        hipLaunchKernelGGL(edge_fused_fallback, dim3((E + 3) / 4), dim3(256), 0, stream,
                           z, ei, W1, b1, W2, b2, out, N, E);
    }
}